// Round 1
// baseline (1206.836 us; speedup 1.0000x reference)
//
#include <hip/hip_runtime.h>
#include <cstdint>
#include <cstddef>

#define DIMX 256
#define DIMV 512
#define DIMH 768
#define EPSV 0.05f

typedef __bf16 bf16x8 __attribute__((ext_vector_type(8)));
typedef unsigned short u16x8 __attribute__((ext_vector_type(8)));
typedef unsigned int u32x4 __attribute__((ext_vector_type(4)));
typedef float f32x4 __attribute__((ext_vector_type(4)));

__device__ __forceinline__ unsigned short f2bf(float f) {
  unsigned int u = __float_as_uint(f);
  u += 0x7fffu + ((u >> 16) & 1u);
  return (unsigned short)(u >> 16);
}
__device__ __forceinline__ float bf2f(unsigned short b) {
  return __uint_as_float(((unsigned int)b) << 16);
}
__device__ __forceinline__ bf16x8 ld8(const unsigned short* p) {
  u16x8 u = *reinterpret_cast<const u16x8*>(p);
  return __builtin_bit_cast(bf16x8, u);
}
__device__ __forceinline__ f32x4 mfma16(bf16x8 a, bf16x8 b, f32x4 c) {
  return __builtin_amdgcn_mfma_f32_16x16x32_bf16(a, b, c, 0, 0, 0);
}

// ---------------- K0: split X into bf16 hi/lo for split-MFMA SYRK ----------------
__global__ void k_split(const float* __restrict__ X, unsigned short* __restrict__ Xhi,
                        unsigned short* __restrict__ Xlo) {
  int idx = blockIdx.x * 256 + threadIdx.x;
  if (idx < DIMH * DIMH) {
    float f = X[idx];
    unsigned short h = f2bf(f);
    Xhi[idx] = h;
    Xlo[idx] = f2bf(f - bf2f(h));
  }
}

// ---------------- K1: P = 0.5*Pstar@Pstar^T + eps*I (fp32, direct) ----------------
__global__ void k_syrkP(const float* __restrict__ A, float* __restrict__ P) {
  int bi = blockIdx.x >> 4, bj = blockIdx.x & 15;
  int ty = threadIdx.x >> 4, tx = threadIdx.x & 15;
  int i = bi * 16 + ty, j = bj * 16 + tx;
  const f32x4* ra = reinterpret_cast<const f32x4*>(A + (size_t)i * DIMX);
  const f32x4* rb = reinterpret_cast<const f32x4*>(A + (size_t)j * DIMX);
  float s = 0.f;
  for (int k = 0; k < 64; ++k) {
    f32x4 a = ra[k], b = rb[k];
    s = fmaf(a[0], b[0], s); s = fmaf(a[1], b[1], s);
    s = fmaf(a[2], b[2], s); s = fmaf(a[3], b[3], s);
  }
  P[(size_t)i * DIMX + j] = 0.5f * s + (i == j ? EPSV : 0.f);
}

// ---------------- K2: H = X@X^T + eps*I via bf16x2 split MFMA ----------------
__global__ __launch_bounds__(256) void k_syrkH(const unsigned short* __restrict__ Xhi,
                                               const unsigned short* __restrict__ Xlo,
                                               float* __restrict__ H) {
  int bx = blockIdx.x % 12, by = blockIdx.x / 12;
  int i0 = by * 64, j0 = bx * 64;
  int l = threadIdx.x & 63, wv = threadIdx.x >> 6;
  int lr = l & 15, lq = l >> 4;
  int koff = lq * 8;
  int arow = i0 + wv * 16 + lr;
  f32x4 z = {0.f, 0.f, 0.f, 0.f};
  f32x4 acc[4] = {z, z, z, z};
  for (int pass = 0; pass < 3; ++pass) {
    const unsigned short* Xa = (pass == 2) ? Xlo : Xhi;
    const unsigned short* Xb = (pass == 1) ? Xlo : Xhi;
    for (int kc = 0; kc < 24; ++kc) {
      bf16x8 a = ld8(&Xa[(size_t)arow * DIMH + kc * 32 + koff]);
#pragma unroll
      for (int ct = 0; ct < 4; ++ct) {
        bf16x8 b = ld8(&Xb[(size_t)(j0 + ct * 16 + lr) * DIMH + kc * 32 + koff]);
        acc[ct] = mfma16(a, b, acc[ct]);
      }
    }
  }
#pragma unroll
  for (int ct = 0; ct < 4; ++ct)
#pragma unroll
    for (int r = 0; r < 4; ++r) {
      int i = i0 + wv * 16 + lq * 4 + r;
      int j = j0 + ct * 16 + lr;
      H[(size_t)i * DIMH + j] = acc[ct][r] + (i == j ? EPSV : 0.f);
    }
}

// ---------------- K3: Pinv = inv(P), single-block register Gauss-Jordan ----------------
__global__ __launch_bounds__(1024) void k_gj256(const float* __restrict__ P,
                                                float* __restrict__ Pinv) {
  __shared__ float rowb[32 * 12];  // row k staged, strided to spread banks
  __shared__ float colb[256];
  int t = threadIdx.x;
  int tr = t >> 5, tc = t & 31;  // 8-row block x 8-col block per thread
  float m[8][8];
#pragma unroll
  for (int i = 0; i < 8; ++i) {
    f32x4 a = *reinterpret_cast<const f32x4*>(&P[(size_t)(8 * tr + i) * 256 + 8 * tc]);
    f32x4 b = *reinterpret_cast<const f32x4*>(&P[(size_t)(8 * tr + i) * 256 + 8 * tc + 4]);
    m[i][0] = a[0]; m[i][1] = a[1]; m[i][2] = a[2]; m[i][3] = a[3];
    m[i][4] = b[0]; m[i][5] = b[1]; m[i][6] = b[2]; m[i][7] = b[3];
  }
  for (int k = 0; k < 256; ++k) {
    int kb = k >> 3, ko = k & 7;
    if (tr == kb) {
#pragma unroll
      for (int r = 0; r < 8; ++r)
        if (r == ko) {
#pragma unroll
          for (int j = 0; j < 8; ++j) rowb[12 * tc + j] = m[r][j];
        }
    }
    if (tc == kb) {
#pragma unroll
      for (int c = 0; c < 8; ++c)
        if (c == ko) {
#pragma unroll
          for (int i = 0; i < 8; ++i) colb[8 * tr + i] = m[i][c];
        }
    }
    __syncthreads();
    float ip = 1.0f / rowb[12 * kb + ko];
    float cv[8], rv[8];
#pragma unroll
    for (int i = 0; i < 8; ++i) cv[i] = colb[8 * tr + i];
#pragma unroll
    for (int j = 0; j < 8; ++j) rv[j] = rowb[12 * tc + j] * ip;
    bool rblk = (tr == kb), cblk = (tc == kb);
#pragma unroll
    for (int i = 0; i < 8; ++i) {
      bool isrk = rblk && (i == ko);
      float ci = cv[i];
#pragma unroll
      for (int j = 0; j < 8; ++j) {
        bool isck = cblk && (j == ko);
        float v = fmaf(-ci, rv[j], m[i][j]);
        if (isck) v = -ci * ip;
        if (isrk) v = rv[j];
        if (isrk && isck) v = ip;
        m[i][j] = v;
      }
    }
    __syncthreads();
  }
#pragma unroll
  for (int i = 0; i < 8; ++i)
#pragma unroll
    for (int j = 0; j < 8; ++j)
      Pinv[(size_t)(8 * tr + i) * 256 + 8 * tc + j] = m[i][j];
}

// ---------------- K4: Gin[c][q] = [C1 | D11] as bf16 ----------------
__global__ void k_gin(const float* __restrict__ H, const float* __restrict__ Chi,
                      unsigned short* __restrict__ Gin) {
  int q = blockIdx.x * 256 + threadIdx.x;  // 0..767
  int c = blockIdx.y;                      // 0..511
  float rlam = 2.f / H[(size_t)(256 + c) * DIMH + 256 + c];
  float v;
  if (q < 256) {
    v = Chi[(size_t)q * DIMV + c] * rlam;
  } else {
    int j = q - 256;
    v = (j < c) ? -H[(size_t)(256 + c) * DIMH + 256 + j] * rlam : 0.f;
  }
  Gin[(size_t)c * DIMH + q] = f2bf(v);
}

// ---------------- K5: Gout = Pinv @ [Y | M] as bf16 (Y,M built on the fly) ----------------
__global__ __launch_bounds__(256) void k_gout(const float* __restrict__ Pinv,
                                              const float* __restrict__ H,
                                              const float* __restrict__ Y1,
                                              const float* __restrict__ Chi,
                                              unsigned short* __restrict__ Gout) {
  __shared__ float Ps[32][33], Bs[32][33];
  int q0 = blockIdx.x * 32, i0 = blockIdx.y * 32;
  int t = threadIdx.x;
  int tx = t & 31, ty = t >> 5;
  int lrr = t >> 3, lc4 = (t & 7) * 4;
  float acc[4] = {0.f, 0.f, 0.f, 0.f};
  for (int kc = 0; kc < 8; ++kc) {
    int k0 = kc * 32;
    f32x4 pv = *reinterpret_cast<const f32x4*>(&Pinv[(size_t)(i0 + lrr) * 256 + k0 + lc4]);
    Ps[lrr][lc4 + 0] = pv[0]; Ps[lrr][lc4 + 1] = pv[1];
    Ps[lrr][lc4 + 2] = pv[2]; Ps[lrr][lc4 + 3] = pv[3];
    int k = k0 + lrr;
#pragma unroll
    for (int e = 0; e < 4; ++e) {
      int q = q0 + lc4 + e;
      float v;
      if (q < 256) {
        v = -0.5f * (H[(size_t)k * DIMH + q] + Y1[(size_t)k * 256 + q] - Y1[(size_t)q * 256 + k]);
      } else {
        int c = q - 256;
        v = -(H[(size_t)k * DIMH + 256 + c] + Chi[(size_t)k * DIMV + c]);
      }
      Bs[lrr][lc4 + e] = v;
    }
    __syncthreads();
#pragma unroll
    for (int kk = 0; kk < 32; ++kk) {
      float bb = Bs[kk][tx];
#pragma unroll
      for (int rr = 0; rr < 4; ++rr) acc[rr] = fmaf(Ps[4 * ty + rr][kk], bb, acc[rr]);
    }
    __syncthreads();
  }
#pragma unroll
  for (int rr = 0; rr < 4; ++rr)
    Gout[(size_t)(i0 + 4 * ty + rr) * DIMH + q0 + tx] = f2bf(acc[rr]);
}

// ---------------- K6: fused main — cx GEMM + blocked tanh recurrence + output GEMM ----------------
// 64 rows/block, 4 waves. wlds: 64 x 520 bf16 (w history). accb: 64 x 33 f32.
__global__ __launch_bounds__(256, 2) void k_main(const float* __restrict__ x,
                                                 const unsigned short* __restrict__ Gin,
                                                 const unsigned short* __restrict__ Gout,
                                                 const float* __restrict__ bv,
                                                 const float* __restrict__ bx,
                                                 float* __restrict__ out) {
  extern __shared__ char smem[];
  unsigned short* wlds = (unsigned short*)smem;          // 64*520*2 = 66560 B
  float* accb = (float*)(smem + 64 * 520 * 2);           // 64*33*4  =  8448 B
  int tid = threadIdx.x;
  int wv = tid >> 6, l = tid & 63;
  int lr = l & 15, lq = l >> 4;
  int koff = lq * 8;
  int rowbase = blockIdx.x * 64;
  int myrow = rowbase + wv * 16 + lr;

  // phase 0: x A-fragments in registers (8 K-chunks x 32)
  bf16x8 xa[8];
  const float* xr = x + (size_t)myrow * 256 + koff;
#pragma unroll
  for (int kc = 0; kc < 8; ++kc) {
    f32x4 f0 = *reinterpret_cast<const f32x4*>(xr + kc * 32);
    f32x4 f1 = *reinterpret_cast<const f32x4*>(xr + kc * 32 + 4);
    u16x8 u;
    u[0] = f2bf(f0[0]); u[1] = f2bf(f0[1]); u[2] = f2bf(f0[2]); u[3] = f2bf(f0[3]);
    u[4] = f2bf(f1[0]); u[5] = f2bf(f1[1]); u[6] = f2bf(f1[2]); u[7] = f2bf(f1[3]);
    xa[kc] = __builtin_bit_cast(bf16x8, u);
  }

  f32x4 z = {0.f, 0.f, 0.f, 0.f};

  // 16 column-blocks of 32
  for (int b = 0; b < 16; ++b) {
    // GEMM: acc[16 rows x 32 cols] = [x | w(<32b)] @ Gin[32b..32b+31]^T
    f32x4 a0 = z, a1 = z;
    const unsigned short* g0 = Gin + (size_t)(32 * b + lr) * DIMH + koff;
    const unsigned short* g1 = g0 + 16 * DIMH;
#pragma unroll
    for (int kc = 0; kc < 8; ++kc) {
      bf16x8 b0 = ld8(g0 + kc * 32);
      bf16x8 b1 = ld8(g1 + kc * 32);
      a0 = mfma16(xa[kc], b0, a0);
      a1 = mfma16(xa[kc], b1, a1);
    }
    for (int kc2 = 0; kc2 < b; ++kc2) {
      bf16x8 aw = ld8(&wlds[(wv * 16 + lr) * 520 + kc2 * 32 + koff]);
      bf16x8 b0 = ld8(g0 + 256 + kc2 * 32);
      bf16x8 b1 = ld8(g1 + 256 + kc2 * 32);
      a0 = mfma16(aw, b0, a0);
      a1 = mfma16(aw, b1, a1);
    }
    // dump accumulators to LDS (C/D layout: col = lane&15, row = (lane>>4)*4+reg)
    int r0 = wv * 16 + lq * 4;
#pragma unroll
    for (int r = 0; r < 4; ++r) {
      accb[(r0 + r) * 33 + lr] = a0[r];
      accb[(r0 + r) * 33 + 16 + lr] = a1[r];
    }
    __syncthreads();
    // serial 32-step tail: wave0 only, one lane per row; D11 rows via uniform scalar loads
    if (wv == 0) {
      float wblk[32];
#pragma unroll
      for (int i = 0; i < 32; ++i) {
        int boff = __builtin_amdgcn_readfirstlane((((32 * b + i) * DIMH) + 256 + 32 * b) * 2);
        const unsigned int* gu = (const unsigned int*)((const char*)Gin + boff);
        float p0 = 0.f, p1 = 0.f, p2 = 0.f, p3 = 0.f;
#pragma unroll
        for (int j = 0; j < i; ++j) {
          unsigned int pw = gu[j >> 1];
          float dj = __uint_as_float((j & 1) ? (pw & 0xffff0000u) : (pw << 16));
          if ((j & 3) == 0) p0 = fmaf(dj, wblk[j], p0);
          else if ((j & 3) == 1) p1 = fmaf(dj, wblk[j], p1);
          else if ((j & 3) == 2) p2 = fmaf(dj, wblk[j], p2);
          else p3 = fmaf(dj, wblk[j], p3);
        }
        float s = accb[l * 33 + i] + ((p0 + p1) + (p2 + p3)) + bv[32 * b + i];
        s = fminf(fmaxf(s, -12.f), 12.f);
        float e = __expf(2.f * s);
        wblk[i] = (e - 1.f) * __builtin_amdgcn_rcpf(e + 1.f);
      }
      // pack 32 w-values to bf16, batched 16B LDS writes
      unsigned int pk[16];
#pragma unroll
      for (int h = 0; h < 16; ++h)
        pk[h] = (unsigned int)f2bf(wblk[2 * h]) | ((unsigned int)f2bf(wblk[2 * h + 1]) << 16);
      u32x4* wp = (u32x4*)&wlds[l * 520 + 32 * b];
      u32x4 w0 = {pk[0], pk[1], pk[2], pk[3]};   wp[0] = w0;
      u32x4 w1 = {pk[4], pk[5], pk[6], pk[7]};   wp[1] = w1;
      u32x4 w2 = {pk[8], pk[9], pk[10], pk[11]}; wp[2] = w2;
      u32x4 w3 = {pk[12], pk[13], pk[14], pk[15]}; wp[3] = w3;
    }
    __syncthreads();
  }

  // final GEMM: out = [x | w] @ Gout^T  (+ bx)
  f32x4 oacc[16];
#pragma unroll
  for (int ct = 0; ct < 16; ++ct) oacc[ct] = z;
#pragma unroll
  for (int kc = 0; kc < 8; ++kc) {
#pragma unroll
    for (int ct = 0; ct < 16; ++ct) {
      bf16x8 bb = ld8(&Gout[(size_t)(ct * 16 + lr) * DIMH + kc * 32 + koff]);
      oacc[ct] = mfma16(xa[kc], bb, oacc[ct]);
    }
  }
  for (int kc2 = 0; kc2 < 16; ++kc2) {
    bf16x8 aw = ld8(&wlds[(wv * 16 + lr) * 520 + kc2 * 32 + koff]);
#pragma unroll
    for (int ct = 0; ct < 16; ++ct) {
      bf16x8 bb = ld8(&Gout[(size_t)(ct * 16 + lr) * DIMH + 256 + kc2 * 32 + koff]);
      oacc[ct] = mfma16(aw, bb, oacc[ct]);
    }
  }
  int orow0 = rowbase + wv * 16 + lq * 4;
#pragma unroll
  for (int ct = 0; ct < 16; ++ct) {
    float bxv = bx[ct * 16 + lr];
#pragma unroll
    for (int r = 0; r < 4; ++r)
      out[(size_t)(orow0 + r) * 256 + ct * 16 + lr] = oacc[ct][r] + bxv;
  }
}

extern "C" void kernel_launch(void* const* d_in, const int* in_sizes, int n_in,
                              void* d_out, int out_size, void* d_ws, size_t ws_size,
                              hipStream_t stream) {
  const float* x   = (const float*)d_in[1];
  const float* Pst = (const float*)d_in[2];
  const float* Chi = (const float*)d_in[3];
  const float* X   = (const float*)d_in[4];
  const float* Y1  = (const float*)d_in[5];
  const float* bv  = (const float*)d_in[8];
  const float* bx  = (const float*)d_in[9];
  float* out = (float*)d_out;

  char* ws = (char*)d_ws;
  const size_t OFF_H    = 0;                       // 768*768*4 = 2359296
  const size_t OFF_P    = 2359296;                 // 256*256*4 =  262144
  const size_t OFF_PINV = 2621440;                 //              262144
  const size_t OFF_XHI  = 2883584;                 // 768*768*2 = 1179648
  const size_t OFF_XLO  = 4063232;                 //             1179648
  const size_t OFF_GIN  = 5242880;                 // 512*768*2 =  786432
  const size_t OFF_GOUT = 6029312;                 // 256*768*2 =  393216
  if (ws_size < 6422528) return;

  float* H    = (float*)(ws + OFF_H);
  float* P    = (float*)(ws + OFF_P);
  float* Pinv = (float*)(ws + OFF_PINV);
  unsigned short* Xhi  = (unsigned short*)(ws + OFF_XHI);
  unsigned short* Xlo  = (unsigned short*)(ws + OFF_XLO);
  unsigned short* Gin  = (unsigned short*)(ws + OFF_GIN);
  unsigned short* Gout = (unsigned short*)(ws + OFF_GOUT);

  k_split<<<2304, 256, 0, stream>>>(X, Xhi, Xlo);
  k_syrkP<<<256, 256, 0, stream>>>(Pst, P);
  k_syrkH<<<144, 256, 0, stream>>>(Xhi, Xlo, H);
  k_gj256<<<1, 1024, 0, stream>>>(P, Pinv);
  dim3 gg(3, 512);
  k_gin<<<gg, 256, 0, stream>>>(H, Chi, Gin);
  dim3 go(24, 8);
  k_gout<<<go, 256, 0, stream>>>(Pinv, H, Y1, Chi, Gout);
  k_main<<<1024, 256, 75008, stream>>>(x, Gin, Gout, bv, bx, out);
}

// Round 2
// 946.296 us; speedup vs baseline: 1.2753x; 1.2753x over previous
//
#include <hip/hip_runtime.h>
#include <cstdint>
#include <cstddef>

#define DIMX 256
#define DIMV 512
#define DIMH 768
#define EPSV 0.05f

typedef __bf16 bf16x8 __attribute__((ext_vector_type(8)));
typedef unsigned short u16x8 __attribute__((ext_vector_type(8)));
typedef unsigned int u32x4 __attribute__((ext_vector_type(4)));
typedef float f32x4 __attribute__((ext_vector_type(4)));

__device__ __forceinline__ unsigned short f2bf(float f) {
  unsigned int u = __float_as_uint(f);
  u += 0x7fffu + ((u >> 16) & 1u);
  return (unsigned short)(u >> 16);
}
__device__ __forceinline__ float bf2f(unsigned short b) {
  return __uint_as_float(((unsigned int)b) << 16);
}
__device__ __forceinline__ bf16x8 ld8(const unsigned short* p) {
  u16x8 u = *reinterpret_cast<const u16x8*>(p);
  return __builtin_bit_cast(bf16x8, u);
}
__device__ __forceinline__ f32x4 mfma16(bf16x8 a, bf16x8 b, f32x4 c) {
  return __builtin_amdgcn_mfma_f32_16x16x32_bf16(a, b, c, 0, 0, 0);
}

// ---------------- K0: split X into bf16 hi/lo for split-MFMA SYRK ----------------
__global__ void k_split(const float* __restrict__ X, unsigned short* __restrict__ Xhi,
                        unsigned short* __restrict__ Xlo) {
  int idx = blockIdx.x * 256 + threadIdx.x;
  if (idx < DIMH * DIMH) {
    float f = X[idx];
    unsigned short h = f2bf(f);
    Xhi[idx] = h;
    Xlo[idx] = f2bf(f - bf2f(h));
  }
}

// ---------------- K1: P = 0.5*Pstar@Pstar^T + eps*I (fp32, direct) ----------------
__global__ void k_syrkP(const float* __restrict__ A, float* __restrict__ P) {
  int bi = blockIdx.x >> 4, bj = blockIdx.x & 15;
  int ty = threadIdx.x >> 4, tx = threadIdx.x & 15;
  int i = bi * 16 + ty, j = bj * 16 + tx;
  const f32x4* ra = reinterpret_cast<const f32x4*>(A + (size_t)i * DIMX);
  const f32x4* rb = reinterpret_cast<const f32x4*>(A + (size_t)j * DIMX);
  float s = 0.f;
  for (int k = 0; k < 64; ++k) {
    f32x4 a = ra[k], b = rb[k];
    s = fmaf(a[0], b[0], s); s = fmaf(a[1], b[1], s);
    s = fmaf(a[2], b[2], s); s = fmaf(a[3], b[3], s);
  }
  P[(size_t)i * DIMX + j] = 0.5f * s + (i == j ? EPSV : 0.f);
}

// ---------------- K2: H = X@X^T + eps*I via bf16x2 split MFMA ----------------
__global__ __launch_bounds__(256) void k_syrkH(const unsigned short* __restrict__ Xhi,
                                               const unsigned short* __restrict__ Xlo,
                                               float* __restrict__ H) {
  int bx = blockIdx.x % 12, by = blockIdx.x / 12;
  int i0 = by * 64, j0 = bx * 64;
  int l = threadIdx.x & 63, wv = threadIdx.x >> 6;
  int lr = l & 15, lq = l >> 4;
  int koff = lq * 8;
  int arow = i0 + wv * 16 + lr;
  f32x4 z = {0.f, 0.f, 0.f, 0.f};
  f32x4 acc[4] = {z, z, z, z};
  for (int pass = 0; pass < 3; ++pass) {
    const unsigned short* Xa = (pass == 2) ? Xlo : Xhi;
    const unsigned short* Xb = (pass == 1) ? Xlo : Xhi;
    for (int kc = 0; kc < 24; ++kc) {
      bf16x8 a = ld8(&Xa[(size_t)arow * DIMH + kc * 32 + koff]);
#pragma unroll
      for (int ct = 0; ct < 4; ++ct) {
        bf16x8 b = ld8(&Xb[(size_t)(j0 + ct * 16 + lr) * DIMH + kc * 32 + koff]);
        acc[ct] = mfma16(a, b, acc[ct]);
      }
    }
  }
#pragma unroll
  for (int ct = 0; ct < 4; ++ct)
#pragma unroll
    for (int r = 0; r < 4; ++r) {
      int i = i0 + wv * 16 + lq * 4 + r;
      int j = j0 + ct * 16 + lr;
      H[(size_t)i * DIMH + j] = acc[ct][r] + (i == j ? EPSV : 0.f);
    }
}

// ---------------- K3: Pinv = inv(P), single-block register Gauss-Jordan ----------------
__global__ __launch_bounds__(1024) void k_gj256(const float* __restrict__ P,
                                                float* __restrict__ Pinv) {
  __shared__ float rowb[32 * 12];
  __shared__ float colb[256];
  int t = threadIdx.x;
  int tr = t >> 5, tc = t & 31;
  float m[8][8];
#pragma unroll
  for (int i = 0; i < 8; ++i) {
    f32x4 a = *reinterpret_cast<const f32x4*>(&P[(size_t)(8 * tr + i) * 256 + 8 * tc]);
    f32x4 b = *reinterpret_cast<const f32x4*>(&P[(size_t)(8 * tr + i) * 256 + 8 * tc + 4]);
    m[i][0] = a[0]; m[i][1] = a[1]; m[i][2] = a[2]; m[i][3] = a[3];
    m[i][4] = b[0]; m[i][5] = b[1]; m[i][6] = b[2]; m[i][7] = b[3];
  }
  for (int k = 0; k < 256; ++k) {
    int kb = k >> 3, ko = k & 7;
    if (tr == kb) {
#pragma unroll
      for (int r = 0; r < 8; ++r)
        if (r == ko) {
#pragma unroll
          for (int j = 0; j < 8; ++j) rowb[12 * tc + j] = m[r][j];
        }
    }
    if (tc == kb) {
#pragma unroll
      for (int c = 0; c < 8; ++c)
        if (c == ko) {
#pragma unroll
          for (int i = 0; i < 8; ++i) colb[8 * tr + i] = m[i][c];
        }
    }
    __syncthreads();
    float ip = 1.0f / rowb[12 * kb + ko];
    float cv[8], rv[8];
#pragma unroll
    for (int i = 0; i < 8; ++i) cv[i] = colb[8 * tr + i];
#pragma unroll
    for (int j = 0; j < 8; ++j) rv[j] = rowb[12 * tc + j] * ip;
    bool rblk = (tr == kb), cblk = (tc == kb);
#pragma unroll
    for (int i = 0; i < 8; ++i) {
      bool isrk = rblk && (i == ko);
      float ci = cv[i];
#pragma unroll
      for (int j = 0; j < 8; ++j) {
        bool isck = cblk && (j == ko);
        float v = fmaf(-ci, rv[j], m[i][j]);
        if (isck) v = -ci * ip;
        if (isrk) v = rv[j];
        if (isrk && isck) v = ip;
        m[i][j] = v;
      }
    }
    __syncthreads();
  }
#pragma unroll
  for (int i = 0; i < 8; ++i)
#pragma unroll
    for (int j = 0; j < 8; ++j)
      Pinv[(size_t)(8 * tr + i) * 256 + 8 * tc + j] = m[i][j];
}

// ---------------- K4: Gin[c][q] = [C1 | D11] as bf16 ----------------
__global__ void k_gin(const float* __restrict__ H, const float* __restrict__ Chi,
                      unsigned short* __restrict__ Gin) {
  int q = blockIdx.x * 256 + threadIdx.x;
  int c = blockIdx.y;
  float rlam = 2.f / H[(size_t)(256 + c) * DIMH + 256 + c];
  float v;
  if (q < 256) {
    v = Chi[(size_t)q * DIMV + c] * rlam;
  } else {
    int j = q - 256;
    v = (j < c) ? -H[(size_t)(256 + c) * DIMH + 256 + j] * rlam : 0.f;
  }
  Gin[(size_t)c * DIMH + q] = f2bf(v);
}

// ---------------- K5: Gout = Pinv @ [Y | M] as bf16 ----------------
__global__ __launch_bounds__(256) void k_gout(const float* __restrict__ Pinv,
                                              const float* __restrict__ H,
                                              const float* __restrict__ Y1,
                                              const float* __restrict__ Chi,
                                              unsigned short* __restrict__ Gout) {
  __shared__ float Ps[32][33], Bs[32][33];
  int q0 = blockIdx.x * 32, i0 = blockIdx.y * 32;
  int t = threadIdx.x;
  int tx = t & 31, ty = t >> 5;
  int lrr = t >> 3, lc4 = (t & 7) * 4;
  float acc[4] = {0.f, 0.f, 0.f, 0.f};
  for (int kc = 0; kc < 8; ++kc) {
    int k0 = kc * 32;
    f32x4 pv = *reinterpret_cast<const f32x4*>(&Pinv[(size_t)(i0 + lrr) * 256 + k0 + lc4]);
    Ps[lrr][lc4 + 0] = pv[0]; Ps[lrr][lc4 + 1] = pv[1];
    Ps[lrr][lc4 + 2] = pv[2]; Ps[lrr][lc4 + 3] = pv[3];
    int k = k0 + lrr;
#pragma unroll
    for (int e = 0; e < 4; ++e) {
      int q = q0 + lc4 + e;
      float v;
      if (q < 256) {
        v = -0.5f * (H[(size_t)k * DIMH + q] + Y1[(size_t)k * 256 + q] - Y1[(size_t)q * 256 + k]);
      } else {
        int c = q - 256;
        v = -(H[(size_t)k * DIMH + 256 + c] + Chi[(size_t)k * DIMV + c]);
      }
      Bs[lrr][lc4 + e] = v;
    }
    __syncthreads();
#pragma unroll
    for (int kk = 0; kk < 32; ++kk) {
      float bb = Bs[kk][tx];
#pragma unroll
      for (int rr = 0; rr < 4; ++rr) acc[rr] = fmaf(Ps[4 * ty + rr][kk], bb, acc[rr]);
    }
    __syncthreads();
  }
#pragma unroll
  for (int rr = 0; rr < 4; ++rr)
    Gout[(size_t)(i0 + 4 * ty + rr) * DIMH + q0 + tx] = f2bf(acc[rr]);
}

// ---------------- K6: fused main v2 — barrier-free, per-wave-independent ----------------
// 4 waves x 32 rows = 128 rows/block, 512 blocks. No __syncthreads.
// LDS per wave: w-history 32x520 bf16 (33280 B) + acc 32x33 f32 (4224 B) + ddiag 2048 B.
#define WSTR 520
#define WBYTES (32 * WSTR * 2)
#define ACCSTR 33
#define ACCBYTES (32 * ACCSTR * 4)
#define DDBYTES 2048
#define SMEM_MAIN (4 * WBYTES + 4 * ACCBYTES + 4 * DDBYTES)  // 158208

__global__ __launch_bounds__(256, 1) void k_main(const float* __restrict__ x,
                                                 const unsigned short* __restrict__ Gin,
                                                 const unsigned short* __restrict__ Gout,
                                                 const float* __restrict__ bv,
                                                 const float* __restrict__ bx,
                                                 float* __restrict__ out) {
  extern __shared__ char smem[];
  int tid = threadIdx.x;
  int wv = tid >> 6, l = tid & 63;
  int lr = l & 15, lq = l >> 4, koff = lq * 8;
  unsigned short* wlds = (unsigned short*)(smem + wv * WBYTES);
  float* accb = (float*)(smem + 4 * WBYTES + wv * ACCBYTES);
  char* ddiag = smem + 4 * WBYTES + 4 * ACCBYTES + wv * DDBYTES;

  int rowbase = blockIdx.x * 128 + wv * 32;

  // x A-fragments: 2 row-tiles x 8 K-chunks, held in registers for the whole kernel
  bf16x8 xa[2][8];
#pragma unroll
  for (int rt = 0; rt < 2; ++rt) {
    const float* xr = x + (size_t)(rowbase + rt * 16 + lr) * 256 + koff;
#pragma unroll
    for (int kc = 0; kc < 8; ++kc) {
      f32x4 f0 = *reinterpret_cast<const f32x4*>(xr + kc * 32);
      f32x4 f1 = *reinterpret_cast<const f32x4*>(xr + kc * 32 + 4);
      u16x8 u;
      u[0] = f2bf(f0[0]); u[1] = f2bf(f0[1]); u[2] = f2bf(f0[2]); u[3] = f2bf(f0[3]);
      u[4] = f2bf(f1[0]); u[5] = f2bf(f1[1]); u[6] = f2bf(f1[2]); u[7] = f2bf(f1[3]);
      xa[rt][kc] = __builtin_bit_cast(bf16x8, u);
    }
  }

  f32x4 z = {0.f, 0.f, 0.f, 0.f};

  for (int b = 0; b < 16; ++b) {
    // stage D11 diag block (32x32 bf16) into per-wave LDS: 2 x (16B/lane)
#pragma unroll
    for (int t = 0; t < 2; ++t) {
      int row = t * 16 + (l >> 2);
      const unsigned short* src =
          Gin + (size_t)(32 * b + row) * DIMH + 256 + 32 * b + (l & 3) * 8;
      u16x8 v = *reinterpret_cast<const u16x8*>(src);
      *reinterpret_cast<u16x8*>(ddiag + t * 1024 + l * 16) = v;
    }

    // GEMM: acc[2 rt][2 ct] = [x | w(<32b)] @ Gin-rows[32b..32b+32)^T
    f32x4 acc00 = z, acc01 = z, acc10 = z, acc11 = z;
    const unsigned short* gb0 = Gin + (size_t)(32 * b + lr) * DIMH + koff;
    const unsigned short* gb1 = Gin + (size_t)(32 * b + 16 + lr) * DIMH + koff;
#pragma unroll
    for (int kc = 0; kc < 8; ++kc) {
      bf16x8 b0 = ld8(gb0 + kc * 32);
      bf16x8 b1 = ld8(gb1 + kc * 32);
      acc00 = mfma16(xa[0][kc], b0, acc00);
      acc01 = mfma16(xa[0][kc], b1, acc01);
      acc10 = mfma16(xa[1][kc], b0, acc10);
      acc11 = mfma16(xa[1][kc], b1, acc11);
    }
    for (int kc2 = 0; kc2 < b; ++kc2) {
      bf16x8 a0 = ld8(wlds + (size_t)lr * WSTR + kc2 * 32 + koff);
      bf16x8 a1 = ld8(wlds + (size_t)(16 + lr) * WSTR + kc2 * 32 + koff);
      bf16x8 b0 = ld8(gb0 + 256 + kc2 * 32);
      bf16x8 b1 = ld8(gb1 + 256 + kc2 * 32);
      acc00 = mfma16(a0, b0, acc00);
      acc01 = mfma16(a0, b1, acc01);
      acc10 = mfma16(a1, b0, acc10);
      acc11 = mfma16(a1, b1, acc11);
    }

    // dump accumulators (+bv) to per-wave accb; C/D layout: col=lane&15, row=(lane>>4)*4+r
    float bv0 = bv[32 * b + lr], bv1 = bv[32 * b + 16 + lr];
#pragma unroll
    for (int r = 0; r < 4; ++r) {
      accb[(lq * 4 + r) * ACCSTR + lr] = acc00[r] + bv0;
      accb[(lq * 4 + r) * ACCSTR + 16 + lr] = acc01[r] + bv1;
      accb[(16 + lq * 4 + r) * ACCSTR + lr] = acc10[r] + bv0;
      accb[(16 + lq * 4 + r) * ACCSTR + 16 + lr] = acc11[r] + bv1;
    }

    // serial 32-step tail: lanes 0..31 (one lane per row), D from LDS broadcast reads
    if (l < 32) {
      const unsigned int* dd = (const unsigned int*)ddiag;
      float wf[32];
      unsigned int wpk[16];
#pragma unroll
      for (int i = 0; i < 32; ++i) {
        float p0 = 0.f, p1 = 0.f;
        const unsigned int* ddr = dd + i * 16;
#pragma unroll
        for (int j = 0; j < i; ++j) {
          unsigned int pw = ddr[j >> 1];
          float dj = __uint_as_float((j & 1) ? (pw & 0xffff0000u) : (pw << 16));
          if (j & 1) p1 = fmaf(dj, wf[j], p1);
          else       p0 = fmaf(dj, wf[j], p0);
        }
        float s = accb[l * ACCSTR + i] + p0 + p1;
        s = fminf(fmaxf(s, -12.f), 12.f);
        float e = __expf(2.f * s);
        float w = (e - 1.f) * __builtin_amdgcn_rcpf(e + 1.f);
        wf[i] = w;
        unsigned int hb = (unsigned int)f2bf(w);
        if (i & 1) wpk[i >> 1] |= hb << 16;
        else       wpk[i >> 1] = hb;
      }
      u32x4* wp = (u32x4*)(wlds + (size_t)l * WSTR + 32 * b);
      u32x4 w0 = {wpk[0], wpk[1], wpk[2], wpk[3]};     wp[0] = w0;
      u32x4 w1 = {wpk[4], wpk[5], wpk[6], wpk[7]};     wp[1] = w1;
      u32x4 w2 = {wpk[8], wpk[9], wpk[10], wpk[11]};   wp[2] = w2;
      u32x4 w3 = {wpk[12], wpk[13], wpk[14], wpk[15]}; wp[3] = w3;
    }
  }

  // final GEMM: out = [x | w] @ Gout^T + bx, column-slab at a time (low reg pressure)
#pragma unroll 1
  for (int ct = 0; ct < 16; ++ct) {
    f32x4 o0 = z, o1 = z;
    const unsigned short* gg = Gout + (size_t)(ct * 16 + lr) * DIMH + koff;
#pragma unroll
    for (int kc = 0; kc < 8; ++kc) {
      bf16x8 bb = ld8(gg + kc * 32);
      o0 = mfma16(xa[0][kc], bb, o0);
      o1 = mfma16(xa[1][kc], bb, o1);
    }
#pragma unroll
    for (int kc2 = 0; kc2 < 16; ++kc2) {
      bf16x8 bb = ld8(gg + 256 + kc2 * 32);
      bf16x8 a0 = ld8(wlds + (size_t)lr * WSTR + kc2 * 32 + koff);
      bf16x8 a1 = ld8(wlds + (size_t)(16 + lr) * WSTR + kc2 * 32 + koff);
      o0 = mfma16(a0, bb, o0);
      o1 = mfma16(a1, bb, o1);
    }
    float bxv = bx[ct * 16 + lr];
#pragma unroll
    for (int r = 0; r < 4; ++r) {
      out[(size_t)(rowbase + lq * 4 + r) * 256 + ct * 16 + lr] = o0[r] + bxv;
      out[(size_t)(rowbase + 16 + lq * 4 + r) * 256 + ct * 16 + lr] = o1[r] + bxv;
    }
  }
}

extern "C" void kernel_launch(void* const* d_in, const int* in_sizes, int n_in,
                              void* d_out, int out_size, void* d_ws, size_t ws_size,
                              hipStream_t stream) {
  const float* x   = (const float*)d_in[1];
  const float* Pst = (const float*)d_in[2];
  const float* Chi = (const float*)d_in[3];
  const float* X   = (const float*)d_in[4];
  const float* Y1  = (const float*)d_in[5];
  const float* bv  = (const float*)d_in[8];
  const float* bx  = (const float*)d_in[9];
  float* out = (float*)d_out;

  char* ws = (char*)d_ws;
  const size_t OFF_H    = 0;
  const size_t OFF_P    = 2359296;
  const size_t OFF_PINV = 2621440;
  const size_t OFF_XHI  = 2883584;
  const size_t OFF_XLO  = 4063232;
  const size_t OFF_GIN  = 5242880;
  const size_t OFF_GOUT = 6029312;
  if (ws_size < 6422528) return;

  float* H    = (float*)(ws + OFF_H);
  float* P    = (float*)(ws + OFF_P);
  float* Pinv = (float*)(ws + OFF_PINV);
  unsigned short* Xhi  = (unsigned short*)(ws + OFF_XHI);
  unsigned short* Xlo  = (unsigned short*)(ws + OFF_XLO);
  unsigned short* Gin  = (unsigned short*)(ws + OFF_GIN);
  unsigned short* Gout = (unsigned short*)(ws + OFF_GOUT);

  k_split<<<2304, 256, 0, stream>>>(X, Xhi, Xlo);
  k_syrkP<<<256, 256, 0, stream>>>(Pst, P);
  k_syrkH<<<144, 256, 0, stream>>>(Xhi, Xlo, H);
  k_gj256<<<1, 1024, 0, stream>>>(P, Pinv);
  dim3 gg(3, 512);
  k_gin<<<gg, 256, 0, stream>>>(H, Chi, Gin);
  dim3 go(24, 8);
  k_gout<<<go, 256, 0, stream>>>(Pinv, H, Y1, Chi, Gout);
  k_main<<<512, 256, SMEM_MAIN, stream>>>(x, Gin, Gout, bv, bx, out);
}

// Round 3
// 810.325 us; speedup vs baseline: 1.4893x; 1.1678x over previous
//
#include <hip/hip_runtime.h>
#include <cstdint>
#include <cstddef>

#define DIMX 256
#define DIMV 512
#define DIMH 768
#define EPSV 0.05f

typedef __bf16 bf16x8 __attribute__((ext_vector_type(8)));
typedef unsigned short u16x8 __attribute__((ext_vector_type(8)));
typedef unsigned int u32x4 __attribute__((ext_vector_type(4)));
typedef float f32x4 __attribute__((ext_vector_type(4)));

__device__ __forceinline__ unsigned short f2bf(float f) {
  unsigned int u = __float_as_uint(f);
  u += 0x7fffu + ((u >> 16) & 1u);
  return (unsigned short)(u >> 16);
}
__device__ __forceinline__ float bf2f(unsigned short b) {
  return __uint_as_float(((unsigned int)b) << 16);
}
__device__ __forceinline__ bf16x8 ld8(const unsigned short* p) {
  u16x8 u = *reinterpret_cast<const u16x8*>(p);
  return __builtin_bit_cast(bf16x8, u);
}
__device__ __forceinline__ f32x4 mfma16(bf16x8 a, bf16x8 b, f32x4 c) {
  return __builtin_amdgcn_mfma_f32_16x16x32_bf16(a, b, c, 0, 0, 0);
}

// ---------------- K0: split X into bf16 hi/lo for split-MFMA SYRK ----------------
__global__ void k_split(const float* __restrict__ X, unsigned short* __restrict__ Xhi,
                        unsigned short* __restrict__ Xlo) {
  int idx = blockIdx.x * 256 + threadIdx.x;
  if (idx < DIMH * DIMH) {
    float f = X[idx];
    unsigned short h = f2bf(f);
    Xhi[idx] = h;
    Xlo[idx] = f2bf(f - bf2f(h));
  }
}

// ---------------- K1: P = 0.5*Pstar@Pstar^T + eps*I (fp32, direct) ----------------
__global__ void k_syrkP(const float* __restrict__ A, float* __restrict__ P) {
  int bi = blockIdx.x >> 4, bj = blockIdx.x & 15;
  int ty = threadIdx.x >> 4, tx = threadIdx.x & 15;
  int i = bi * 16 + ty, j = bj * 16 + tx;
  const f32x4* ra = reinterpret_cast<const f32x4*>(A + (size_t)i * DIMX);
  const f32x4* rb = reinterpret_cast<const f32x4*>(A + (size_t)j * DIMX);
  float s = 0.f;
  for (int k = 0; k < 64; ++k) {
    f32x4 a = ra[k], b = rb[k];
    s = fmaf(a[0], b[0], s); s = fmaf(a[1], b[1], s);
    s = fmaf(a[2], b[2], s); s = fmaf(a[3], b[3], s);
  }
  P[(size_t)i * DIMX + j] = 0.5f * s + (i == j ? EPSV : 0.f);
}

// ---------------- K2: H = X@X^T + eps*I via bf16x2 split MFMA ----------------
__global__ __launch_bounds__(256) void k_syrkH(const unsigned short* __restrict__ Xhi,
                                               const unsigned short* __restrict__ Xlo,
                                               float* __restrict__ H) {
  int bx = blockIdx.x % 12, by = blockIdx.x / 12;
  int i0 = by * 64, j0 = bx * 64;
  int l = threadIdx.x & 63, wv = threadIdx.x >> 6;
  int lr = l & 15, lq = l >> 4;
  int koff = lq * 8;
  int arow = i0 + wv * 16 + lr;
  f32x4 z = {0.f, 0.f, 0.f, 0.f};
  f32x4 acc[4] = {z, z, z, z};
  for (int pass = 0; pass < 3; ++pass) {
    const unsigned short* Xa = (pass == 2) ? Xlo : Xhi;
    const unsigned short* Xb = (pass == 1) ? Xlo : Xhi;
    for (int kc = 0; kc < 24; ++kc) {
      bf16x8 a = ld8(&Xa[(size_t)arow * DIMH + kc * 32 + koff]);
#pragma unroll
      for (int ct = 0; ct < 4; ++ct) {
        bf16x8 b = ld8(&Xb[(size_t)(j0 + ct * 16 + lr) * DIMH + kc * 32 + koff]);
        acc[ct] = mfma16(a, b, acc[ct]);
      }
    }
  }
#pragma unroll
  for (int ct = 0; ct < 4; ++ct)
#pragma unroll
    for (int r = 0; r < 4; ++r) {
      int i = i0 + wv * 16 + lq * 4 + r;
      int j = j0 + ct * 16 + lr;
      H[(size_t)i * DIMH + j] = acc[ct][r] + (i == j ? EPSV : 0.f);
    }
}

// ---------------- K3: Pinv = inv(P), single-block register Gauss-Jordan ----------------
__global__ __launch_bounds__(1024) void k_gj256(const float* __restrict__ P,
                                                float* __restrict__ Pinv) {
  __shared__ float rowb[32 * 12];
  __shared__ float colb[256];
  int t = threadIdx.x;
  int tr = t >> 5, tc = t & 31;
  float m[8][8];
#pragma unroll
  for (int i = 0; i < 8; ++i) {
    f32x4 a = *reinterpret_cast<const f32x4*>(&P[(size_t)(8 * tr + i) * 256 + 8 * tc]);
    f32x4 b = *reinterpret_cast<const f32x4*>(&P[(size_t)(8 * tr + i) * 256 + 8 * tc + 4]);
    m[i][0] = a[0]; m[i][1] = a[1]; m[i][2] = a[2]; m[i][3] = a[3];
    m[i][4] = b[0]; m[i][5] = b[1]; m[i][6] = b[2]; m[i][7] = b[3];
  }
  for (int k = 0; k < 256; ++k) {
    int kb = k >> 3, ko = k & 7;
    if (tr == kb) {
#pragma unroll
      for (int r = 0; r < 8; ++r)
        if (r == ko) {
#pragma unroll
          for (int j = 0; j < 8; ++j) rowb[12 * tc + j] = m[r][j];
        }
    }
    if (tc == kb) {
#pragma unroll
      for (int c = 0; c < 8; ++c)
        if (c == ko) {
#pragma unroll
          for (int i = 0; i < 8; ++i) colb[8 * tr + i] = m[i][c];
        }
    }
    __syncthreads();
    float ip = 1.0f / rowb[12 * kb + ko];
    float cv[8], rv[8];
#pragma unroll
    for (int i = 0; i < 8; ++i) cv[i] = colb[8 * tr + i];
#pragma unroll
    for (int j = 0; j < 8; ++j) rv[j] = rowb[12 * tc + j] * ip;
    bool rblk = (tr == kb), cblk = (tc == kb);
#pragma unroll
    for (int i = 0; i < 8; ++i) {
      bool isrk = rblk && (i == ko);
      float ci = cv[i];
#pragma unroll
      for (int j = 0; j < 8; ++j) {
        bool isck = cblk && (j == ko);
        float v = fmaf(-ci, rv[j], m[i][j]);
        if (isck) v = -ci * ip;
        if (isrk) v = rv[j];
        if (isrk && isck) v = ip;
        m[i][j] = v;
      }
    }
    __syncthreads();
  }
#pragma unroll
  for (int i = 0; i < 8; ++i)
#pragma unroll
    for (int j = 0; j < 8; ++j)
      Pinv[(size_t)(8 * tr + i) * 256 + 8 * tc + j] = m[i][j];
}

// ---------------- K4: Gin[c][q] = [C1 | D11] as bf16 ----------------
__global__ void k_gin(const float* __restrict__ H, const float* __restrict__ Chi,
                      unsigned short* __restrict__ Gin) {
  int q = blockIdx.x * 256 + threadIdx.x;
  int c = blockIdx.y;
  float rlam = 2.f / H[(size_t)(256 + c) * DIMH + 256 + c];
  float v;
  if (q < 256) {
    v = Chi[(size_t)q * DIMV + c] * rlam;
  } else {
    int j = q - 256;
    v = (j < c) ? -H[(size_t)(256 + c) * DIMH + 256 + j] * rlam : 0.f;
  }
  Gin[(size_t)c * DIMH + q] = f2bf(v);
}

// ---------------- K5: Gout = Pinv @ [Y | M] as bf16 ----------------
__global__ __launch_bounds__(256) void k_gout(const float* __restrict__ Pinv,
                                              const float* __restrict__ H,
                                              const float* __restrict__ Y1,
                                              const float* __restrict__ Chi,
                                              unsigned short* __restrict__ Gout) {
  __shared__ float Ps[32][33], Bs[32][33];
  int q0 = blockIdx.x * 32, i0 = blockIdx.y * 32;
  int t = threadIdx.x;
  int tx = t & 31, ty = t >> 5;
  int lrr = t >> 3, lc4 = (t & 7) * 4;
  float acc[4] = {0.f, 0.f, 0.f, 0.f};
  for (int kc = 0; kc < 8; ++kc) {
    int k0 = kc * 32;
    f32x4 pv = *reinterpret_cast<const f32x4*>(&Pinv[(size_t)(i0 + lrr) * 256 + k0 + lc4]);
    Ps[lrr][lc4 + 0] = pv[0]; Ps[lrr][lc4 + 1] = pv[1];
    Ps[lrr][lc4 + 2] = pv[2]; Ps[lrr][lc4 + 3] = pv[3];
    int k = k0 + lrr;
#pragma unroll
    for (int e = 0; e < 4; ++e) {
      int q = q0 + lc4 + e;
      float v;
      if (q < 256) {
        v = -0.5f * (H[(size_t)k * DIMH + q] + Y1[(size_t)k * 256 + q] - Y1[(size_t)q * 256 + k]);
      } else {
        int c = q - 256;
        v = -(H[(size_t)k * DIMH + 256 + c] + Chi[(size_t)k * DIMV + c]);
      }
      Bs[lrr][lc4 + e] = v;
    }
    __syncthreads();
#pragma unroll
    for (int kk = 0; kk < 32; ++kk) {
      float bb = Bs[kk][tx];
#pragma unroll
      for (int rr = 0; rr < 4; ++rr) acc[rr] = fmaf(Ps[4 * ty + rr][kk], bb, acc[rr]);
    }
    __syncthreads();
  }
#pragma unroll
  for (int rr = 0; rr < 4; ++rr)
    Gout[(size_t)(i0 + 4 * ty + rr) * DIMH + q0 + tx] = f2bf(acc[rr]);
}

// ---------------- K6: fused main v3 — [x|w] A-operand entirely in registers ----------------
// 4 waves x 32 rows = 128 rows/block, 512 blocks, no barriers.
// LDS/wave: accb 32*33*4=4224 | ddiag 2048 | wtmp 32*80=2560  -> 8832; block = 35328 B.
#define ACCSTR 33
#define ACC_W 4224
#define DD_W 2048
#define WT_W 2560
#define SMEM_MAIN (4 * (ACC_W + DD_W + WT_W))

__global__ __launch_bounds__(256, 2) void k_main(const float* __restrict__ x,
                                                 const unsigned short* __restrict__ Gin,
                                                 const unsigned short* __restrict__ Gout,
                                                 const float* __restrict__ bv,
                                                 const float* __restrict__ bx,
                                                 float* __restrict__ out) {
  extern __shared__ char smem[];
  int tid = threadIdx.x;
  int wv = tid >> 6, l = tid & 63;
  int lr = l & 15, lq = l >> 4, koff = lq * 8;
  float* accb = (float*)(smem + wv * ACC_W);
  char* ddiag = smem + 4 * ACC_W + wv * DD_W;
  char* wtmp = smem + 4 * ACC_W + 4 * DD_W + wv * WT_W;

  int rowbase = blockIdx.x * 128 + wv * 32;

  // persistent A-operand fragments: chunks 0..7 = x, 8..23 = w (filled as blocks complete)
  bf16x8 frag0[24], frag1[24];
  {
    u16x8 zz = {0, 0, 0, 0, 0, 0, 0, 0};
#pragma unroll
    for (int c = 8; c < 24; ++c) {
      frag0[c] = __builtin_bit_cast(bf16x8, zz);
      frag1[c] = __builtin_bit_cast(bf16x8, zz);
    }
  }
#pragma unroll
  for (int kc = 0; kc < 8; ++kc) {
    const float* xr0 = x + (size_t)(rowbase + lr) * 256 + koff + kc * 32;
    const float* xr1 = x + (size_t)(rowbase + 16 + lr) * 256 + koff + kc * 32;
    f32x4 a0 = *reinterpret_cast<const f32x4*>(xr0);
    f32x4 a1 = *reinterpret_cast<const f32x4*>(xr0 + 4);
    f32x4 b0 = *reinterpret_cast<const f32x4*>(xr1);
    f32x4 b1 = *reinterpret_cast<const f32x4*>(xr1 + 4);
    u16x8 u0, u1;
#pragma unroll
    for (int e = 0; e < 4; ++e) {
      u0[e] = f2bf(a0[e]); u0[4 + e] = f2bf(a1[e]);
      u1[e] = f2bf(b0[e]); u1[4 + e] = f2bf(b1[e]);
    }
    frag0[kc] = __builtin_bit_cast(bf16x8, u0);
    frag1[kc] = __builtin_bit_cast(bf16x8, u1);
  }

  f32x4 z = {0.f, 0.f, 0.f, 0.f};

#pragma unroll 1
  for (int b = 0; b < 16; ++b) {
    // stage D11 diag block (32x32 bf16, row-major) into per-wave LDS
#pragma unroll
    for (int t = 0; t < 2; ++t) {
      int row = t * 16 + (l >> 2);
      const unsigned short* src =
          Gin + (size_t)(32 * b + row) * DIMH + 256 + 32 * b + (l & 3) * 8;
      u16x8 v = *reinterpret_cast<const u16x8*>(src);
      *reinterpret_cast<u16x8*>(ddiag + t * 1024 + l * 16) = v;
    }

    // prefix GEMM: acc = [x | w(<b)] @ Gin-rows[32b..32b+32)^T  (zero-padded chunks)
    f32x4 a00 = z, a01 = z, a10 = z, a11 = z;
    const unsigned short* gb0 = Gin + (size_t)(32 * b + lr) * DIMH + koff;
    const unsigned short* gb1 = gb0 + 16 * DIMH;
#pragma unroll
    for (int g = 0; g < 6; ++g) {
      if (g * 4 < 8 + b) {  // uniform scalar branch; zero frag chunks pad the tail
#pragma unroll
        for (int cc = 0; cc < 4; ++cc) {
          int c = g * 4 + cc;
          bf16x8 bb0 = ld8(gb0 + c * 32);
          bf16x8 bb1 = ld8(gb1 + c * 32);
          a00 = mfma16(frag0[c], bb0, a00);
          a01 = mfma16(frag0[c], bb1, a01);
          a10 = mfma16(frag1[c], bb0, a10);
          a11 = mfma16(frag1[c], bb1, a11);
        }
      }
    }

    // dump acc (+bv) to per-wave accb
    float bv0 = bv[32 * b + lr], bv1 = bv[32 * b + 16 + lr];
#pragma unroll
    for (int r = 0; r < 4; ++r) {
      accb[(lq * 4 + r) * ACCSTR + lr] = a00[r] + bv0;
      accb[(lq * 4 + r) * ACCSTR + 16 + lr] = a01[r] + bv1;
      accb[(16 + lq * 4 + r) * ACCSTR + lr] = a10[r] + bv0;
      accb[(16 + lq * 4 + r) * ACCSTR + 16 + lr] = a11[r] + bv1;
    }

    // serial 32-step tail on lanes 0..31 (lane = row)
    if (l < 32) {
      const unsigned int* dd = (const unsigned int*)ddiag;
      float wf[32];
      unsigned int wpk[16];
#pragma unroll
      for (int i = 0; i < 32; ++i) {
        float p0 = 0.f, p1 = 0.f;
        const unsigned int* ddr = dd + i * 16;
#pragma unroll
        for (int j = 0; j < i; ++j) {
          unsigned int pw = ddr[j >> 1];
          float dj = __uint_as_float((j & 1) ? (pw & 0xffff0000u) : (pw << 16));
          if (j & 1) p1 = fmaf(dj, wf[j], p1);
          else       p0 = fmaf(dj, wf[j], p0);
        }
        float s = accb[l * ACCSTR + i] + p0 + p1;
        s = fminf(fmaxf(s, -12.f), 12.f);
        float e = __expf(2.f * s);
        float w = (e - 1.f) * __builtin_amdgcn_rcpf(e + 1.f);
        wf[i] = w;
        unsigned int hb = (unsigned int)f2bf(w);
        if (i & 1) wpk[i >> 1] |= hb << 16;
        else       wpk[i >> 1] = hb;
      }
      u32x4* wp = (u32x4*)(wtmp + l * 80);
      u32x4 w0 = {wpk[0], wpk[1], wpk[2], wpk[3]};     wp[0] = w0;
      u32x4 w1 = {wpk[4], wpk[5], wpk[6], wpk[7]};     wp[1] = w1;
      u32x4 w2 = {wpk[8], wpk[9], wpk[10], wpk[11]};   wp[2] = w2;
      u32x4 w3 = {wpk[12], wpk[13], wpk[14], wpk[15]}; wp[3] = w3;
    }

    // redistribute: all 64 lanes pick up their A-fragment of this w block
    bf16x8 nw0 = ld8((const unsigned short*)(wtmp + lr * 80 + lq * 16));
    bf16x8 nw1 = ld8((const unsigned short*)(wtmp + (16 + lr) * 80 + lq * 16));
#pragma unroll
    for (int j = 0; j < 16; ++j) {
      if (b == j) { frag0[8 + j] = nw0; frag1[8 + j] = nw1; }
    }
  }

  // final GEMM: out = [x | w] @ Gout^T + bx
#pragma unroll 1
  for (int ct = 0; ct < 16; ++ct) {
    f32x4 o0 = z, o1 = z;
    const unsigned short* gg = Gout + (size_t)(ct * 16 + lr) * DIMH + koff;
#pragma unroll
    for (int c = 0; c < 24; ++c) {
      bf16x8 bb = ld8(gg + c * 32);
      o0 = mfma16(frag0[c], bb, o0);
      o1 = mfma16(frag1[c], bb, o1);
    }
    float bxv = bx[ct * 16 + lr];
#pragma unroll
    for (int r = 0; r < 4; ++r) {
      out[(size_t)(rowbase + lq * 4 + r) * 256 + ct * 16 + lr] = o0[r] + bxv;
      out[(size_t)(rowbase + 16 + lq * 4 + r) * 256 + ct * 16 + lr] = o1[r] + bxv;
    }
  }
}

extern "C" void kernel_launch(void* const* d_in, const int* in_sizes, int n_in,
                              void* d_out, int out_size, void* d_ws, size_t ws_size,
                              hipStream_t stream) {
  const float* x   = (const float*)d_in[1];
  const float* Pst = (const float*)d_in[2];
  const float* Chi = (const float*)d_in[3];
  const float* X   = (const float*)d_in[4];
  const float* Y1  = (const float*)d_in[5];
  const float* bv  = (const float*)d_in[8];
  const float* bx  = (const float*)d_in[9];
  float* out = (float*)d_out;

  char* ws = (char*)d_ws;
  const size_t OFF_H    = 0;
  const size_t OFF_P    = 2359296;
  const size_t OFF_PINV = 2621440;
  const size_t OFF_XHI  = 2883584;
  const size_t OFF_XLO  = 4063232;
  const size_t OFF_GIN  = 5242880;
  const size_t OFF_GOUT = 6029312;
  if (ws_size < 6422528) return;

  float* H    = (float*)(ws + OFF_H);
  float* P    = (float*)(ws + OFF_P);
  float* Pinv = (float*)(ws + OFF_PINV);
  unsigned short* Xhi  = (unsigned short*)(ws + OFF_XHI);
  unsigned short* Xlo  = (unsigned short*)(ws + OFF_XLO);
  unsigned short* Gin  = (unsigned short*)(ws + OFF_GIN);
  unsigned short* Gout = (unsigned short*)(ws + OFF_GOUT);

  k_split<<<2304, 256, 0, stream>>>(X, Xhi, Xlo);
  k_syrkP<<<256, 256, 0, stream>>>(Pst, P);
  k_syrkH<<<144, 256, 0, stream>>>(Xhi, Xlo, H);
  k_gj256<<<1, 1024, 0, stream>>>(P, Pinv);
  dim3 gg(3, 512);
  k_gin<<<gg, 256, 0, stream>>>(H, Chi, Gin);
  dim3 go(24, 8);
  k_gout<<<go, 256, 0, stream>>>(Pinv, H, Y1, Chi, Gout);
  k_main<<<512, 256, SMEM_MAIN, stream>>>(x, Gin, Gout, bv, bx, out);
}

// Round 4
// 808.739 us; speedup vs baseline: 1.4922x; 1.0020x over previous
//
#include <hip/hip_runtime.h>
#include <cstdint>
#include <cstddef>

#define DIMX 256
#define DIMV 512
#define DIMH 768
#define EPSV 0.05f

typedef __bf16 bf16x8 __attribute__((ext_vector_type(8)));
typedef unsigned short u16x8 __attribute__((ext_vector_type(8)));
typedef unsigned int u32x4 __attribute__((ext_vector_type(4)));
typedef float f32x4 __attribute__((ext_vector_type(4)));

__device__ __forceinline__ unsigned short f2bf(float f) {
  unsigned int u = __float_as_uint(f);
  u += 0x7fffu + ((u >> 16) & 1u);
  return (unsigned short)(u >> 16);
}
__device__ __forceinline__ float bf2f(unsigned short b) {
  return __uint_as_float(((unsigned int)b) << 16);
}
__device__ __forceinline__ bf16x8 ld8(const unsigned short* p) {
  u16x8 u = *reinterpret_cast<const u16x8*>(p);
  return __builtin_bit_cast(bf16x8, u);
}
__device__ __forceinline__ f32x4 mfma16(bf16x8 a, bf16x8 b, f32x4 c) {
  return __builtin_amdgcn_mfma_f32_16x16x32_bf16(a, b, c, 0, 0, 0);
}

// ---------------- K0: split X into bf16 hi/lo for split-MFMA SYRK ----------------
__global__ void k_split(const float* __restrict__ X, unsigned short* __restrict__ Xhi,
                        unsigned short* __restrict__ Xlo) {
  int idx = blockIdx.x * 256 + threadIdx.x;
  if (idx < DIMH * DIMH) {
    float f = X[idx];
    unsigned short h = f2bf(f);
    Xhi[idx] = h;
    Xlo[idx] = f2bf(f - bf2f(h));
  }
}

// ---------------- K1: P = 0.5*Pstar@Pstar^T + eps*I (fp32, direct) ----------------
__global__ void k_syrkP(const float* __restrict__ A, float* __restrict__ P) {
  int bi = blockIdx.x >> 4, bj = blockIdx.x & 15;
  int ty = threadIdx.x >> 4, tx = threadIdx.x & 15;
  int i = bi * 16 + ty, j = bj * 16 + tx;
  const f32x4* ra = reinterpret_cast<const f32x4*>(A + (size_t)i * DIMX);
  const f32x4* rb = reinterpret_cast<const f32x4*>(A + (size_t)j * DIMX);
  float s = 0.f;
  for (int k = 0; k < 64; ++k) {
    f32x4 a = ra[k], b = rb[k];
    s = fmaf(a[0], b[0], s); s = fmaf(a[1], b[1], s);
    s = fmaf(a[2], b[2], s); s = fmaf(a[3], b[3], s);
  }
  P[(size_t)i * DIMX + j] = 0.5f * s + (i == j ? EPSV : 0.f);
}

// ---------------- K2: H = X@X^T + eps*I via bf16x2 split MFMA ----------------
__global__ __launch_bounds__(256) void k_syrkH(const unsigned short* __restrict__ Xhi,
                                               const unsigned short* __restrict__ Xlo,
                                               float* __restrict__ H) {
  int bx = blockIdx.x % 12, by = blockIdx.x / 12;
  int i0 = by * 64, j0 = bx * 64;
  int l = threadIdx.x & 63, wv = threadIdx.x >> 6;
  int lr = l & 15, lq = l >> 4;
  int koff = lq * 8;
  int arow = i0 + wv * 16 + lr;
  f32x4 z = {0.f, 0.f, 0.f, 0.f};
  f32x4 acc[4] = {z, z, z, z};
  for (int pass = 0; pass < 3; ++pass) {
    const unsigned short* Xa = (pass == 2) ? Xlo : Xhi;
    const unsigned short* Xb = (pass == 1) ? Xlo : Xhi;
    for (int kc = 0; kc < 24; ++kc) {
      bf16x8 a = ld8(&Xa[(size_t)arow * DIMH + kc * 32 + koff]);
#pragma unroll
      for (int ct = 0; ct < 4; ++ct) {
        bf16x8 b = ld8(&Xb[(size_t)(j0 + ct * 16 + lr) * DIMH + kc * 32 + koff]);
        acc[ct] = mfma16(a, b, acc[ct]);
      }
    }
  }
#pragma unroll
  for (int ct = 0; ct < 4; ++ct)
#pragma unroll
    for (int r = 0; r < 4; ++r) {
      int i = i0 + wv * 16 + lq * 4 + r;
      int j = j0 + ct * 16 + lr;
      H[(size_t)i * DIMH + j] = acc[ct][r] + (i == j ? EPSV : 0.f);
    }
}

// ---------------- K3: Pinv = inv(P), single-block register Gauss-Jordan ----------------
// __launch_bounds__(1024, 4): block is 16 waves = 4 waves/SIMD physically; declaring it
// lifts the VGPR cap to 128 so m[8][8] (+rv/cv) stays in registers. Without it the
// compiler targeted 8 waves/SIMD (64-VGPR cap) and spilled the whole matrix to scratch
// (round-3 profile: VGPR_Count=48, 437 us vs ~27 us VALU floor).
__global__ __launch_bounds__(1024, 4) void k_gj256(const float* __restrict__ P,
                                                   float* __restrict__ Pinv) {
  __shared__ float rowb[32 * 12];
  __shared__ float colb[256];
  int t = threadIdx.x;
  int tr = t >> 5, tc = t & 31;
  float m[8][8];
#pragma unroll
  for (int i = 0; i < 8; ++i) {
    f32x4 a = *reinterpret_cast<const f32x4*>(&P[(size_t)(8 * tr + i) * 256 + 8 * tc]);
    f32x4 b = *reinterpret_cast<const f32x4*>(&P[(size_t)(8 * tr + i) * 256 + 8 * tc + 4]);
    m[i][0] = a[0]; m[i][1] = a[1]; m[i][2] = a[2]; m[i][3] = a[3];
    m[i][4] = b[0]; m[i][5] = b[1]; m[i][6] = b[2]; m[i][7] = b[3];
  }
  for (int k = 0; k < 256; ++k) {
    int kb = k >> 3, ko = k & 7;
    if (tr == kb) {
#pragma unroll
      for (int r = 0; r < 8; ++r)
        if (r == ko) {
#pragma unroll
          for (int j = 0; j < 8; ++j) rowb[12 * tc + j] = m[r][j];
        }
    }
    if (tc == kb) {
#pragma unroll
      for (int c = 0; c < 8; ++c)
        if (c == ko) {
#pragma unroll
          for (int i = 0; i < 8; ++i) colb[8 * tr + i] = m[i][c];
        }
    }
    __syncthreads();
    float ip = 1.0f / rowb[12 * kb + ko];
    float cv[8], rv[8];
#pragma unroll
    for (int i = 0; i < 8; ++i) cv[i] = colb[8 * tr + i];
#pragma unroll
    for (int j = 0; j < 8; ++j) rv[j] = rowb[12 * tc + j] * ip;
    bool rblk = (tr == kb), cblk = (tc == kb);
#pragma unroll
    for (int i = 0; i < 8; ++i) {
      bool isrk = rblk && (i == ko);
      float ci = cv[i];
#pragma unroll
      for (int j = 0; j < 8; ++j) {
        bool isck = cblk && (j == ko);
        float v = fmaf(-ci, rv[j], m[i][j]);
        if (isck) v = -ci * ip;
        if (isrk) v = rv[j];
        if (isrk && isck) v = ip;
        m[i][j] = v;
      }
    }
    __syncthreads();
  }
#pragma unroll
  for (int i = 0; i < 8; ++i)
#pragma unroll
    for (int j = 0; j < 8; ++j)
      Pinv[(size_t)(8 * tr + i) * 256 + 8 * tc + j] = m[i][j];
}

// ---------------- K4: Gin[c][q] = [C1 | D11] as bf16 ----------------
__global__ void k_gin(const float* __restrict__ H, const float* __restrict__ Chi,
                      unsigned short* __restrict__ Gin) {
  int q = blockIdx.x * 256 + threadIdx.x;
  int c = blockIdx.y;
  float rlam = 2.f / H[(size_t)(256 + c) * DIMH + 256 + c];
  float v;
  if (q < 256) {
    v = Chi[(size_t)q * DIMV + c] * rlam;
  } else {
    int j = q - 256;
    v = (j < c) ? -H[(size_t)(256 + c) * DIMH + 256 + j] * rlam : 0.f;
  }
  Gin[(size_t)c * DIMH + q] = f2bf(v);
}

// ---------------- K5: Gout = Pinv @ [Y | M] as bf16 ----------------
__global__ __launch_bounds__(256) void k_gout(const float* __restrict__ Pinv,
                                              const float* __restrict__ H,
                                              const float* __restrict__ Y1,
                                              const float* __restrict__ Chi,
                                              unsigned short* __restrict__ Gout) {
  __shared__ float Ps[32][33], Bs[32][33];
  int q0 = blockIdx.x * 32, i0 = blockIdx.y * 32;
  int t = threadIdx.x;
  int tx = t & 31, ty = t >> 5;
  int lrr = t >> 3, lc4 = (t & 7) * 4;
  float acc[4] = {0.f, 0.f, 0.f, 0.f};
  for (int kc = 0; kc < 8; ++kc) {
    int k0 = kc * 32;
    f32x4 pv = *reinterpret_cast<const f32x4*>(&Pinv[(size_t)(i0 + lrr) * 256 + k0 + lc4]);
    Ps[lrr][lc4 + 0] = pv[0]; Ps[lrr][lc4 + 1] = pv[1];
    Ps[lrr][lc4 + 2] = pv[2]; Ps[lrr][lc4 + 3] = pv[3];
    int k = k0 + lrr;
#pragma unroll
    for (int e = 0; e < 4; ++e) {
      int q = q0 + lc4 + e;
      float v;
      if (q < 256) {
        v = -0.5f * (H[(size_t)k * DIMH + q] + Y1[(size_t)k * 256 + q] - Y1[(size_t)q * 256 + k]);
      } else {
        int c = q - 256;
        v = -(H[(size_t)k * DIMH + 256 + c] + Chi[(size_t)k * DIMV + c]);
      }
      Bs[lrr][lc4 + e] = v;
    }
    __syncthreads();
#pragma unroll
    for (int kk = 0; kk < 32; ++kk) {
      float bb = Bs[kk][tx];
#pragma unroll
      for (int rr = 0; rr < 4; ++rr) acc[rr] = fmaf(Ps[4 * ty + rr][kk], bb, acc[rr]);
    }
    __syncthreads();
  }
#pragma unroll
  for (int rr = 0; rr < 4; ++rr)
    Gout[(size_t)(i0 + 4 * ty + rr) * DIMH + q0 + tx] = f2bf(acc[rr]);
}

// ---------------- K6: fused main v3 — [x|w] A-operand entirely in registers ----------------
// (unchanged this round: will read its counters next profile when it is the top dispatch)
#define ACCSTR 33
#define ACC_W 4224
#define DD_W 2048
#define WT_W 2560
#define SMEM_MAIN (4 * (ACC_W + DD_W + WT_W))

__global__ __launch_bounds__(256, 2) void k_main(const float* __restrict__ x,
                                                 const unsigned short* __restrict__ Gin,
                                                 const unsigned short* __restrict__ Gout,
                                                 const float* __restrict__ bv,
                                                 const float* __restrict__ bx,
                                                 float* __restrict__ out) {
  extern __shared__ char smem[];
  int tid = threadIdx.x;
  int wv = tid >> 6, l = tid & 63;
  int lr = l & 15, lq = l >> 4, koff = lq * 8;
  float* accb = (float*)(smem + wv * ACC_W);
  char* ddiag = smem + 4 * ACC_W + wv * DD_W;
  char* wtmp = smem + 4 * ACC_W + 4 * DD_W + wv * WT_W;

  int rowbase = blockIdx.x * 128 + wv * 32;

  // persistent A-operand fragments: chunks 0..7 = x, 8..23 = w (filled as blocks complete)
  bf16x8 frag0[24], frag1[24];
  {
    u16x8 zz = {0, 0, 0, 0, 0, 0, 0, 0};
#pragma unroll
    for (int c = 8; c < 24; ++c) {
      frag0[c] = __builtin_bit_cast(bf16x8, zz);
      frag1[c] = __builtin_bit_cast(bf16x8, zz);
    }
  }
#pragma unroll
  for (int kc = 0; kc < 8; ++kc) {
    const float* xr0 = x + (size_t)(rowbase + lr) * 256 + koff + kc * 32;
    const float* xr1 = x + (size_t)(rowbase + 16 + lr) * 256 + koff + kc * 32;
    f32x4 a0 = *reinterpret_cast<const f32x4*>(xr0);
    f32x4 a1 = *reinterpret_cast<const f32x4*>(xr0 + 4);
    f32x4 b0 = *reinterpret_cast<const f32x4*>(xr1);
    f32x4 b1 = *reinterpret_cast<const f32x4*>(xr1 + 4);
    u16x8 u0, u1;
#pragma unroll
    for (int e = 0; e < 4; ++e) {
      u0[e] = f2bf(a0[e]); u0[4 + e] = f2bf(a1[e]);
      u1[e] = f2bf(b0[e]); u1[4 + e] = f2bf(b1[e]);
    }
    frag0[kc] = __builtin_bit_cast(bf16x8, u0);
    frag1[kc] = __builtin_bit_cast(bf16x8, u1);
  }

  f32x4 z = {0.f, 0.f, 0.f, 0.f};

#pragma unroll 1
  for (int b = 0; b < 16; ++b) {
    // stage D11 diag block (32x32 bf16, row-major) into per-wave LDS
#pragma unroll
    for (int t = 0; t < 2; ++t) {
      int row = t * 16 + (l >> 2);
      const unsigned short* src =
          Gin + (size_t)(32 * b + row) * DIMH + 256 + 32 * b + (l & 3) * 8;
      u16x8 v = *reinterpret_cast<const u16x8*>(src);
      *reinterpret_cast<u16x8*>(ddiag + t * 1024 + l * 16) = v;
    }

    // prefix GEMM: acc = [x | w(<b)] @ Gin-rows[32b..32b+32)^T  (zero-padded chunks)
    f32x4 a00 = z, a01 = z, a10 = z, a11 = z;
    const unsigned short* gb0 = Gin + (size_t)(32 * b + lr) * DIMH + koff;
    const unsigned short* gb1 = gb0 + 16 * DIMH;
#pragma unroll
    for (int g = 0; g < 6; ++g) {
      if (g * 4 < 8 + b) {  // uniform scalar branch; zero frag chunks pad the tail
#pragma unroll
        for (int cc = 0; cc < 4; ++cc) {
          int c = g * 4 + cc;
          bf16x8 bb0 = ld8(gb0 + c * 32);
          bf16x8 bb1 = ld8(gb1 + c * 32);
          a00 = mfma16(frag0[c], bb0, a00);
          a01 = mfma16(frag0[c], bb1, a01);
          a10 = mfma16(frag1[c], bb0, a10);
          a11 = mfma16(frag1[c], bb1, a11);
        }
      }
    }

    // dump acc (+bv) to per-wave accb
    float bv0 = bv[32 * b + lr], bv1 = bv[32 * b + 16 + lr];
#pragma unroll
    for (int r = 0; r < 4; ++r) {
      accb[(lq * 4 + r) * ACCSTR + lr] = a00[r] + bv0;
      accb[(lq * 4 + r) * ACCSTR + 16 + lr] = a01[r] + bv1;
      accb[(16 + lq * 4 + r) * ACCSTR + lr] = a10[r] + bv0;
      accb[(16 + lq * 4 + r) * ACCSTR + 16 + lr] = a11[r] + bv1;
    }

    // serial 32-step tail on lanes 0..31 (lane = row)
    if (l < 32) {
      const unsigned int* dd = (const unsigned int*)ddiag;
      float wf[32];
      unsigned int wpk[16];
#pragma unroll
      for (int i = 0; i < 32; ++i) {
        float p0 = 0.f, p1 = 0.f;
        const unsigned int* ddr = dd + i * 16;
#pragma unroll
        for (int j = 0; j < i; ++j) {
          unsigned int pw = ddr[j >> 1];
          float dj = __uint_as_float((j & 1) ? (pw & 0xffff0000u) : (pw << 16));
          if (j & 1) p1 = fmaf(dj, wf[j], p1);
          else       p0 = fmaf(dj, wf[j], p0);
        }
        float s = accb[l * ACCSTR + i] + p0 + p1;
        s = fminf(fmaxf(s, -12.f), 12.f);
        float e = __expf(2.f * s);
        float w = (e - 1.f) * __builtin_amdgcn_rcpf(e + 1.f);
        wf[i] = w;
        unsigned int hb = (unsigned int)f2bf(w);
        if (i & 1) wpk[i >> 1] |= hb << 16;
        else       wpk[i >> 1] = hb;
      }
      u32x4* wp = (u32x4*)(wtmp + l * 80);
      u32x4 w0 = {wpk[0], wpk[1], wpk[2], wpk[3]};     wp[0] = w0;
      u32x4 w1 = {wpk[4], wpk[5], wpk[6], wpk[7]};     wp[1] = w1;
      u32x4 w2 = {wpk[8], wpk[9], wpk[10], wpk[11]};   wp[2] = w2;
      u32x4 w3 = {wpk[12], wpk[13], wpk[14], wpk[15]}; wp[3] = w3;
    }

    // redistribute: all 64 lanes pick up their A-fragment of this w block
    bf16x8 nw0 = ld8((const unsigned short*)(wtmp + lr * 80 + lq * 16));
    bf16x8 nw1 = ld8((const unsigned short*)(wtmp + (16 + lr) * 80 + lq * 16));
#pragma unroll
    for (int j = 0; j < 16; ++j) {
      if (b == j) { frag0[8 + j] = nw0; frag1[8 + j] = nw1; }
    }
  }

  // final GEMM: out = [x | w] @ Gout^T + bx
#pragma unroll 1
  for (int ct = 0; ct < 16; ++ct) {
    f32x4 o0 = z, o1 = z;
    const unsigned short* gg = Gout + (size_t)(ct * 16 + lr) * DIMH + koff;
#pragma unroll
    for (int c = 0; c < 24; ++c) {
      bf16x8 bb = ld8(gg + c * 32);
      o0 = mfma16(frag0[c], bb, o0);
      o1 = mfma16(frag1[c], bb, o1);
    }
    float bxv = bx[ct * 16 + lr];
#pragma unroll
    for (int r = 0; r < 4; ++r) {
      out[(size_t)(rowbase + lq * 4 + r) * 256 + ct * 16 + lr] = o0[r] + bxv;
      out[(size_t)(rowbase + 16 + lq * 4 + r) * 256 + ct * 16 + lr] = o1[r] + bxv;
    }
  }
}

extern "C" void kernel_launch(void* const* d_in, const int* in_sizes, int n_in,
                              void* d_out, int out_size, void* d_ws, size_t ws_size,
                              hipStream_t stream) {
  const float* x   = (const float*)d_in[1];
  const float* Pst = (const float*)d_in[2];
  const float* Chi = (const float*)d_in[3];
  const float* X   = (const float*)d_in[4];
  const float* Y1  = (const float*)d_in[5];
  const float* bv  = (const float*)d_in[8];
  const float* bx  = (const float*)d_in[9];
  float* out = (float*)d_out;

  char* ws = (char*)d_ws;
  const size_t OFF_H    = 0;
  const size_t OFF_P    = 2359296;
  const size_t OFF_PINV = 2621440;
  const size_t OFF_XHI  = 2883584;
  const size_t OFF_XLO  = 4063232;
  const size_t OFF_GIN  = 5242880;
  const size_t OFF_GOUT = 6029312;
  if (ws_size < 6422528) return;

  float* H    = (float*)(ws + OFF_H);
  float* P    = (float*)(ws + OFF_P);
  float* Pinv = (float*)(ws + OFF_PINV);
  unsigned short* Xhi  = (unsigned short*)(ws + OFF_XHI);
  unsigned short* Xlo  = (unsigned short*)(ws + OFF_XLO);
  unsigned short* Gin  = (unsigned short*)(ws + OFF_GIN);
  unsigned short* Gout = (unsigned short*)(ws + OFF_GOUT);

  k_split<<<2304, 256, 0, stream>>>(X, Xhi, Xlo);
  k_syrkP<<<256, 256, 0, stream>>>(Pst, P);
  k_syrkH<<<144, 256, 0, stream>>>(Xhi, Xlo, H);
  k_gj256<<<1, 1024, 0, stream>>>(P, Pinv);
  dim3 gg(3, 512);
  k_gin<<<gg, 256, 0, stream>>>(H, Chi, Gin);
  dim3 go(24, 8);
  k_gout<<<go, 256, 0, stream>>>(Pinv, H, Y1, Chi, Gout);
  k_main<<<512, 256, SMEM_MAIN, stream>>>(x, Gin, Gout, bv, bx, out);
}